// Round 4
// baseline (790.215 us; speedup 1.0000x reference)
//
#include <hip/hip_runtime.h>

// Grouped GEMM (ragged rows over 8 experts) + dequant epilogue.
// out[m,n] = (sum_k a[m,k]*b[e(m),n,k]) * scale_a[m] * scale_b[e(m)]
// M=16384, K=2048, N=5632, E=8.
// R4: convert f32->bf16 once into d_ws, then 256x256-tile GEMM with a
// 4-slot K-slice LDS ring, counted vmcnt(8) (T3+T4), XOR bank swizzle (T2),
// setprio around MFMA (T5), XCD-aware block swizzle (T1).

#define KSLICE 32
#define NSLICE 64  // K / KSLICE
#define BM 256
#define BN 256

typedef __attribute__((ext_vector_type(4))) float f32x4;
typedef __attribute__((ext_vector_type(4))) unsigned int u32x4;
using frag_ab = __attribute__((ext_vector_type(8))) short;  // 8 bf16
using frag_cd = __attribute__((ext_vector_type(4))) float;  // 4 f32

// round-to-nearest-even f32 -> bf16, packed pair
__device__ __forceinline__ unsigned int pack_bf2(float x, float y) {
  unsigned int ux = __float_as_uint(x);
  unsigned int uy = __float_as_uint(y);
  ux += 0x7fffu + ((ux >> 16) & 1u);
  uy += 0x7fffu + ((uy >> 16) & 1u);
  return (ux >> 16) | (uy & 0xffff0000u);
}

__device__ __forceinline__ void gload_lds16(const void* g, void* lds) {
  __builtin_amdgcn_global_load_lds(
      (const __attribute__((address_space(1))) unsigned int*)g,
      (__attribute__((address_space(3))) unsigned int*)lds, 16, 0, 0);
}

// ---------------- convert pass: f32 -> bf16 into ws ----------------
__global__ __launch_bounds__(256)
void convert_kernel(const float* __restrict__ A, const float* __restrict__ B,
                    unsigned short* __restrict__ wa, unsigned short* __restrict__ wb) {
  constexpr long long NA = 16384LL * 2048;
  constexpr long long NB = 8LL * 5632 * 2048;
  constexpr long long NA8 = NA / 8;
  constexpr long long NTOT = (NA + NB) / 8;
  for (long long c = (long long)blockIdx.x * 256 + threadIdx.x; c < NTOT;
       c += (long long)gridDim.x * 256) {
    const float* src;
    unsigned short* dst;
    long long off;
    if (c < NA8) { src = A; dst = wa; off = c * 8; }
    else         { src = B; dst = wb; off = (c - NA8) * 8; }
    f32x4 v0 = *(const f32x4*)(src + off);
    f32x4 v1 = *(const f32x4*)(src + off + 4);
    u32x4 o;
    o[0] = pack_bf2(v0[0], v0[1]);
    o[1] = pack_bf2(v0[2], v0[3]);
    o[2] = pack_bf2(v1[0], v1[1]);
    o[3] = pack_bf2(v1[2], v1[3]);
    *(u32x4*)(dst + off) = o;
  }
}

// ---------------- deep-pipelined bf16 grouped GEMM ----------------
// LDS ring: 4 slots per operand; slot = [256 rows][32 k] bf16 = 16 KiB.
// Physical layout within a slot (swizzled, rule #21 both-sides):
//   logical (r, k): rp=r>>1, slot8=((r&1)<<2)|(k>>3)  (8 16B-chunks / 128B row-pair)
//   phys_el = rp*64 + ((slot8 ^ (rp&7)) << 3) + (k&7)
// gload_lds writes linearly (wave base + lane*16B); the per-lane GLOBAL
// address is pre-permuted so data lands at its swizzled physical slot.
__global__ __launch_bounds__(512, 2)
void ggemm8(const unsigned short* __restrict__ A,
            const unsigned short* __restrict__ B,
            const float* __restrict__ sa,
            const float* __restrict__ sb,
            const int* __restrict__ seg,
            float* __restrict__ C) {
  constexpr int M = 16384, K = 2048, N = 5632, E = 8;
  constexpr int NT = N / BN;            // 22
  const int nwg = (M / BM) * NT;        // 1408, % 8 == 0

  int bid = blockIdx.x;
  int sid = (bid & 7) * (nwg >> 3) + (bid >> 3);   // T1 XCD swizzle
  int mt = sid / NT, nt = sid % NT;
  int m0 = mt * BM, n0 = nt * BN;

  int tid = threadIdx.x;
  int lane = tid & 63;
  int w = tid >> 6;                     // 0..7
  int wrow = (w >> 2) * 128;            // 2 wave-rows x 4 wave-cols
  int wcol = (w & 3) * 64;
  int l16 = lane & 15, lhi = lane >> 4;

  __shared__ unsigned short Alds[4 * 8192];  // 64 KiB
  __shared__ unsigned short Blds[4 * 8192];  // 64 KiB

  // ---- per-lane pre-permuted STAGE source coordinates ----
  // wave w, instr i in {0,1} covers 16 rows starting at (w*2+i)*16.
  // lane l writes phys chunk (rp_local = l>>3, slot_phys = l&7);
  // it must fetch logical slot8 = (l&7) ^ (l>>3).
  int rpl = lane >> 3;
  int slog = (lane & 7) ^ rpl;
  int srow = rpl * 2 + (slog >> 2);     // 0..15 within the 16-row block
  int sk0 = (slog & 3) * 8;             // k offset 0/8/16/24
  const unsigned short* gA0 = A + (size_t)(m0 + w * 32 + srow) * K + sk0;
  const unsigned short* gA1 = gA0 + (size_t)16 * K;
  // wave-uniform LDS dests (1024 B per instr)
  unsigned short* ldsA0 = &Alds[(w * 2 + 0) * 512];
  unsigned short* ldsA1 = &Alds[(w * 2 + 1) * 512];
  unsigned short* ldsB0 = &Blds[(w * 2 + 0) * 512];
  unsigned short* ldsB1 = &Blds[(w * 2 + 1) * 512];

  // ---- per-lane swizzled ds_read offsets (elements within a slot) ----
  int offA[8], offB[4];
#pragma unroll
  for (int i = 0; i < 8; ++i) {
    int r = wrow + i * 16 + l16;
    int rp = r >> 1;
    int sl = ((r & 1) << 2) | lhi;
    offA[i] = rp * 64 + ((sl ^ (rp & 7)) << 3);
  }
#pragma unroll
  for (int j = 0; j < 4; ++j) {
    int r = wcol + j * 16 + l16;
    int rp = r >> 1;
    int sl = ((r & 1) << 2) | lhi;
    offB[j] = rp * 64 + ((sl ^ (rp & 7)) << 3);
  }

  for (int e = 0; e < E; ++e) {
    int rlo = max(m0, seg[e]);
    int rhi = min(m0 + BM, seg[e + 1]);
    if (rlo >= rhi) continue;  // uniform across block

    const unsigned short* gB0 =
        B + (size_t)e * N * K + (size_t)(n0 + w * 32 + srow) * K + sk0;
    const unsigned short* gB1 = gB0 + (size_t)16 * K;

    frag_cd acc[8][4];
#pragma unroll
    for (int i = 0; i < 8; ++i)
#pragma unroll
      for (int j = 0; j < 4; ++j) acc[i][j] = (frag_cd){0.f, 0.f, 0.f, 0.f};

    auto stage = [&](int s) {
      int slot = (s & 3) * 8192;
      int g = s * KSLICE;
      gload_lds16(gA0 + g, ldsA0 + slot);
      gload_lds16(gA1 + g, ldsA1 + slot);
      gload_lds16(gB0 + g, ldsB0 + slot);
      gload_lds16(gB1 + g, ldsB1 + slot);
    };

    // phase s: read+compute slice s, stage slice s+3, counted vmcnt wait.
    auto phase = [&](int s, auto vmwait) {
      int slot = (s & 3) * 8192;
      frag_ab af[8], bf[4];
#pragma unroll
      for (int i = 0; i < 8; ++i)
        af[i] = *(const frag_ab*)(&Alds[slot + offA[i]]);
#pragma unroll
      for (int j = 0; j < 4; ++j)
        bf[j] = *(const frag_ab*)(&Blds[slot + offB[j]]);
      if (s + 3 < NSLICE) stage(s + 3);
      vmwait();
      __builtin_amdgcn_s_barrier();      // all waves' slice s+1 landed
      asm volatile("s_waitcnt lgkmcnt(0)" ::: "memory");
      __builtin_amdgcn_s_setprio(1);
#pragma unroll
      for (int i = 0; i < 8; ++i)
#pragma unroll
        for (int j = 0; j < 4; ++j)
          acc[i][j] = __builtin_amdgcn_mfma_f32_16x16x32_bf16(
              af[i], bf[j], acc[i][j], 0, 0, 0);
      __builtin_amdgcn_s_setprio(0);
      __builtin_amdgcn_s_barrier();      // slot (s+2)&3 may be overwritten next
    };

    auto W8 = [] { asm volatile("s_waitcnt vmcnt(8)" ::: "memory"); };
    auto W4 = [] { asm volatile("s_waitcnt vmcnt(4)" ::: "memory"); };
    auto W0 = [] { asm volatile("s_waitcnt vmcnt(0)" ::: "memory"); };

    // prologue: 3 slices in flight, slice 0 landed
    stage(0); stage(1); stage(2);
    asm volatile("s_waitcnt vmcnt(8)" ::: "memory");
    __builtin_amdgcn_s_barrier();

#pragma unroll 4
    for (int s = 0; s < NSLICE - 4; ++s) phase(s, W8);
    phase(NSLICE - 4, W8);   // stages slice 63; waits slice 61
    phase(NSLICE - 3, W4);   // waits slice 62
    phase(NSLICE - 2, W0);   // waits slice 63 (tail drain)
    phase(NSLICE - 1, W0);

    // epilogue: dequant + masked store of rows [rlo, rhi)
    float sbe = sb[e];
#pragma unroll
    for (int i = 0; i < 8; ++i) {
#pragma unroll
      for (int r = 0; r < 4; ++r) {
        int grow = m0 + wrow + i * 16 + lhi * 4 + r;
        if (grow >= rlo && grow < rhi) {
          float s = sa[grow] * sbe;
          float* Crow = C + (size_t)grow * N + n0 + wcol;
#pragma unroll
          for (int j = 0; j < 4; ++j)
            Crow[j * 16 + l16] = acc[i][j][r] * s;
        }
      }
    }
  }
}

extern "C" void kernel_launch(void* const* d_in, const int* in_sizes, int n_in,
                              void* d_out, int out_size, void* d_ws, size_t ws_size,
                              hipStream_t stream) {
  const float* a = (const float*)d_in[0];
  const float* b = (const float*)d_in[1];
  const float* sa = (const float*)d_in[2];
  const float* sb = (const float*)d_in[3];
  const int* seg = (const int*)d_in[4];
  float* out = (float*)d_out;

  constexpr size_t NA = 16384ULL * 2048;
  constexpr size_t NB = 8ULL * 5632 * 2048;
  unsigned short* wa = (unsigned short*)d_ws;
  unsigned short* wb = wa + NA;

  hipLaunchKernelGGL(convert_kernel, dim3(2048), dim3(256), 0, stream, a, b, wa, wb);
  hipLaunchKernelGGL(ggemm8, dim3((16384 / BM) * (5632 / BN)), dim3(512), 0, stream,
                     wa, wb, sa, sb, seg, out);
}

// Round 5
// 757.600 us; speedup vs baseline: 1.0431x; 1.0431x over previous
//
#include <hip/hip_runtime.h>

// Grouped GEMM (ragged rows over 8 experts) + dequant epilogue.
// R5: convert f32->bf16 into d_ws, then 256x256 GEMM with quadrant-cooperative
// 4-phase schedule: stages land 7 phases before first read, one vmcnt(8)/tile.

#define BK 64
#define NTILES 32   // 2048 / 64
#define BM 256
#define BN 256
#define KDIM 2048

typedef __attribute__((ext_vector_type(4))) float f32x4;
typedef __attribute__((ext_vector_type(4))) unsigned int u32x4;
using frag_ab = __attribute__((ext_vector_type(8))) short;  // 8 bf16
using frag_cd = __attribute__((ext_vector_type(4))) float;  // 4 f32

__device__ __forceinline__ unsigned int pack_bf2(float x, float y) {
  unsigned int ux = __float_as_uint(x);
  unsigned int uy = __float_as_uint(y);
  ux += 0x7fffu + ((ux >> 16) & 1u);
  uy += 0x7fffu + ((uy >> 16) & 1u);
  return (ux >> 16) | (uy & 0xffff0000u);
}

__device__ __forceinline__ void gload_lds16(const void* g, void* lds) {
  __builtin_amdgcn_global_load_lds(
      (const __attribute__((address_space(1))) unsigned int*)g,
      (__attribute__((address_space(3))) unsigned int*)lds, 16, 0, 0);
}

// ---------------- convert pass: f32 -> bf16 into ws ----------------
__global__ __launch_bounds__(256)
void convert_kernel(const float* __restrict__ A, const float* __restrict__ B,
                    unsigned short* __restrict__ wa, unsigned short* __restrict__ wb) {
  constexpr long long NA = 16384LL * 2048;
  constexpr long long NB = 8LL * 5632 * 2048;
  constexpr long long NA8 = NA / 8;
  constexpr long long NTOT = (NA + NB) / 8;
  for (long long c = (long long)blockIdx.x * 256 + threadIdx.x; c < NTOT;
       c += (long long)gridDim.x * 256) {
    const float* src;
    unsigned short* dst;
    long long off;
    if (c < NA8) { src = A; dst = wa; off = c * 8; }
    else         { src = B; dst = wb; off = (c - NA8) * 8; }
    f32x4 v0 = *(const f32x4*)(src + off);
    f32x4 v1 = *(const f32x4*)(src + off + 4);
    u32x4 o;
    o[0] = pack_bf2(v0[0], v0[1]);
    o[1] = pack_bf2(v0[2], v0[3]);
    o[2] = pack_bf2(v1[0], v1[1]);
    o[3] = pack_bf2(v1[2], v1[3]);
    *(u32x4*)(dst + off) = o;
  }
}

// ---------------- quadrant-scheduled bf16 grouped GEMM ----------------
// LDS: [buf][op A/B][half][128 rows x 64 k] bf16, 128 KiB total.
// Swizzle: global chunk c (16B) of row r stored at phys chunk c ^ (r&7);
// gload_lds dest linear, global source pre-permuted (both-sides, rule 21).
// Per phase all 8 waves compute one 128x128 block-quadrant (16 MFMA/wave):
//   p1: q0 (hA0,hB0)  reads af(hA0), bf0(hB0)
//   p2: q2 (hA0,hB1)  reads bf1(hB1); stages hA0,hB0 of tile t+2
//   p3: q3 (hA1,hB1)  reads af(hA1); stages hB1(t+2)
//   p4: q1 (hA1,hB0)  no reads; stages hA1(t+2); vmcnt(8); barrier
// Each staged half lands >=7 phases before its first read.
__global__ __launch_bounds__(512, 2)
void ggemm_q(const unsigned short* __restrict__ A,
             const unsigned short* __restrict__ B,
             const float* __restrict__ sa,
             const float* __restrict__ sb,
             const int* __restrict__ seg,
             float* __restrict__ C) {
  constexpr int M = 16384, N = 5632, E = 8;
  constexpr int NTC = N / BN;            // 22
  const int nwg = (M / BM) * NTC;        // 1408, % 8 == 0

  int bid = blockIdx.x;
  int sid = (bid & 7) * (nwg >> 3) + (bid >> 3);  // T1 XCD swizzle
  int mt = sid / NTC, nt = sid % NTC;
  int m0 = mt * BM, n0 = nt * BN;

  int tid = threadIdx.x, lane = tid & 63, w = tid >> 6;
  int l16 = lane & 15, lhi = lane >> 4;
  int rw = (w & 1) * 64;   // wave row offset within a 128-row quadrant
  int cw = (w >> 1) * 32;  // wave col offset within a 128-col quadrant

  __shared__ unsigned short lds[2][2][2][8192];  // [buf][op][half][128*64]

  // ds_read swizzled per-lane offsets (shorts)
  int c7 = l16 & 7;
  int x0 = (lhi ^ c7) * 8;          // ks=0 chunk
  int x1 = ((4 | lhi) ^ c7) * 8;    // ks=1 chunk
  int offA = (rw + l16) * 64;
  int offB = (cw + l16) * 64;
  // stage: per-lane pre-swizzled global source coords
  int srow = lane >> 3;                   // local row 0..7
  int scol = ((lane & 7) ^ srow) * 8;     // pre-permuted col chunk

  const unsigned short* gA = A + (size_t)(m0 + w * 16 + srow) * KDIM + scol;

  frag_ab af[2][4], bf0[2][2], bf1[2][2];

  for (int e = 0; e < E; ++e) {
    int rlo = max(m0, seg[e]);
    int rhi = min(m0 + BM, seg[e + 1]);
    if (rlo >= rhi) continue;
    const unsigned short* gB =
        B + (size_t)e * N * KDIM + (size_t)(n0 + w * 16 + srow) * KDIM + scol;

    frag_cd acc[4][4][2];
#pragma unroll
    for (int qi = 0; qi < 4; ++qi)
#pragma unroll
      for (int f = 0; f < 4; ++f)
#pragma unroll
        for (int g = 0; g < 2; ++g) acc[qi][f][g] = (frag_cd){0.f, 0.f, 0.f, 0.f};

    auto stA = [&](int buf, int half, int t) {
#pragma unroll
      for (int i = 0; i < 2; ++i)
        gload_lds16(gA + (size_t)(half * 128 + i * 8) * KDIM + t * BK,
                    &lds[buf][0][half][(w * 16 + i * 8) * 64]);
    };
    auto stB = [&](int buf, int half, int t) {
#pragma unroll
      for (int i = 0; i < 2; ++i)
        gload_lds16(gB + (size_t)(half * 128 + i * 8) * KDIM + t * BK,
                    &lds[buf][1][half][(w * 16 + i * 8) * 64]);
    };
    auto rdAf = [&](int buf, int half) {
      const unsigned short* p = &lds[buf][0][half][0];
#pragma unroll
      for (int f = 0; f < 4; ++f) {
        af[0][f] = *(const frag_ab*)(p + offA + f * 1024 + x0);
        af[1][f] = *(const frag_ab*)(p + offA + f * 1024 + x1);
      }
    };
    auto rdBf = [&](int buf, int half, frag_ab (&bf)[2][2]) {
      const unsigned short* p = &lds[buf][1][half][0];
#pragma unroll
      for (int g = 0; g < 2; ++g) {
        bf[0][g] = *(const frag_ab*)(p + offB + g * 1024 + x0);
        bf[1][g] = *(const frag_ab*)(p + offB + g * 1024 + x1);
      }
    };
    auto mfma16 = [&](int qi, frag_ab (&bf)[2][2]) {
      __builtin_amdgcn_s_setprio(1);
#pragma unroll
      for (int f = 0; f < 4; ++f)
#pragma unroll
        for (int g = 0; g < 2; ++g)
#pragma unroll
          for (int ks = 0; ks < 2; ++ks)
            acc[qi][f][g] = __builtin_amdgcn_mfma_f32_16x16x32_bf16(
                af[ks][f], bf[ks][g], acc[qi][f][g], 0, 0, 0);
      __builtin_amdgcn_s_setprio(0);
    };

    // prologue: tiles 0,1 fully staged (16 loads); tile 0 landed
    stA(0, 0, 0); stB(0, 0, 0); stB(0, 1, 0); stA(0, 1, 0);
    stA(1, 0, 1); stB(1, 0, 1); stB(1, 1, 1); stA(1, 1, 1);
    asm volatile("s_waitcnt vmcnt(8)" ::: "memory");
    __builtin_amdgcn_s_barrier();

    auto tile_body = [&](int t, int buf) {
      bool st = (t + 2 < NTILES);
      // p1: q0 (hA0, hB0)
      rdAf(buf, 0);
      rdBf(buf, 0, bf0);
      __builtin_amdgcn_s_barrier();
      mfma16(0, bf0);
      // p2: q2 (hA0, hB1) — hA0/hB0 LDS halves now free
      rdBf(buf, 1, bf1);
      if (st) { stA(buf, 0, t + 2); stB(buf, 0, t + 2); }
      __builtin_amdgcn_s_barrier();
      mfma16(1, bf1);
      // p3: q3 (hA1, hB1) — hB1 free after these reads... (reads precede stage)
      rdAf(buf, 1);
      if (st) stB(buf, 1, t + 2);
      __builtin_amdgcn_s_barrier();
      mfma16(2, bf1);
      // p4: q1 (hA1, hB0) — register-held; hA1 LDS free
      if (st) stA(buf, 1, t + 2);
      if (t < NTILES - 2) {
        asm volatile("s_waitcnt vmcnt(8)" ::: "memory");  // next tile landed
      } else if (t == NTILES - 2) {
        asm volatile("s_waitcnt vmcnt(0)" ::: "memory");  // tail drain
      }
      __builtin_amdgcn_s_barrier();
      mfma16(3, bf0);
    };

    for (int t2 = 0; t2 < NTILES; t2 += 2) {
      tile_body(t2, 0);
      tile_body(t2 + 1, 1);
    }

    // epilogue: dequant + masked store
    const int QMAP[4] = {0, 2, 3, 1};
    float sbe = sb[e];
#pragma unroll
    for (int qi = 0; qi < 4; ++qi) {
      int q = QMAP[qi];
      int rbase = m0 + (q & 1) * 128 + rw;
      int cbase = n0 + (q >> 1) * 128 + cw;
#pragma unroll
      for (int f = 0; f < 4; ++f) {
#pragma unroll
        for (int r = 0; r < 4; ++r) {
          int grow = rbase + f * 16 + lhi * 4 + r;
          if (grow >= rlo && grow < rhi) {
            float s = sa[grow] * sbe;
            float* Crow = C + (size_t)grow * N + cbase;
#pragma unroll
            for (int g = 0; g < 2; ++g)
              Crow[g * 16 + l16] = acc[qi][f][g][r] * s;
          }
        }
      }
    }
  }
}

extern "C" void kernel_launch(void* const* d_in, const int* in_sizes, int n_in,
                              void* d_out, int out_size, void* d_ws, size_t ws_size,
                              hipStream_t stream) {
  const float* a = (const float*)d_in[0];
  const float* b = (const float*)d_in[1];
  const float* sa = (const float*)d_in[2];
  const float* sb = (const float*)d_in[3];
  const int* seg = (const int*)d_in[4];
  float* out = (float*)d_out;

  constexpr size_t NA = 16384ULL * 2048;
  unsigned short* wa = (unsigned short*)d_ws;
  unsigned short* wb = wa + NA;

  hipLaunchKernelGGL(convert_kernel, dim3(2048), dim3(256), 0, stream, a, b, wa, wb);
  hipLaunchKernelGGL(ggemm_q, dim3((16384 / BM) * (5632 / BN)), dim3(512), 0, stream,
                     wa, wb, sa, sb, seg, out);
}